// Round 9
// baseline (385.744 us; speedup 1.0000x reference)
//
#include <hip/hip_runtime.h>
#include <hip/hip_bf16.h>

#define BSZ 4
#define SEQ 2048
#define DMODEL 1024
#define DINNER 2048
#define DSTATE 64
#define NH 32
#define HD 64
#define CKL 64            // chunk length
#define NCH 32            // chunks per sequence
#define CONVD 2176
#define DPROJ 4256
#define N1 4224           // GEMM1 N = DINNER + CONVD = 22*192
#define MTOT 8192         // BSZ*SEQ
#define YSTR 72           // LDS row stride (bf16): 144 B = 36 dwords (== 4 mod 32: b128 reads conflict-free)
#define YSTR2 120         // transpose arrays: 240 B = 60 dwords (== 28 mod 32) + 8*(row>>3) column shift
#define CVTB 6272         // blocks of k_pre2 doing weight-convert role

typedef __hip_bfloat16 bf16;
typedef __attribute__((ext_vector_type(8))) short short8;   // 8 bf16 (4 VGPRs)
typedef __attribute__((ext_vector_type(4))) short short4_;  // 8 bytes
typedef __attribute__((ext_vector_type(4))) float f32x4;

__device__ __forceinline__ float sigmoidf_(float x) { return 1.0f / (1.0f + __expf(-x)); }
__device__ __forceinline__ float bits2f(short s) { return __uint_as_float(((unsigned)(unsigned short)s) << 16); }
__device__ __forceinline__ short f2bits(float f) {
    bf16 h = __float2bfloat16(f);
    return *reinterpret_cast<short*>(&h);
}

__device__ __forceinline__ void gl_lds16(const bf16* g, bf16* l) {
    __builtin_amdgcn_global_load_lds((const __attribute__((address_space(1))) void*)g,
                                     (__attribute__((address_space(3))) void*)l, 16, 0, 0);
}

__device__ __forceinline__ f32x4 MF(short8 a, short8 b, f32x4 c) {
    return __builtin_amdgcn_mfma_f32_16x16x32_bf16(a, b, c, 0, 0, 0);
}

// counted s_waitcnt vmcnt(N); "memory" clobber = compiler fence.
template<int N> __device__ __forceinline__ void vmw() {
    if constexpr (N == 0)      asm volatile("s_waitcnt vmcnt(0)" ::: "memory");
    else if constexpr (N == 3) asm volatile("s_waitcnt vmcnt(3)" ::: "memory");
    else if constexpr (N == 6) asm volatile("s_waitcnt vmcnt(6)" ::: "memory");
    else                       asm volatile("s_waitcnt vmcnt(15)" ::: "memory");
}

// XCD-chunked locality swizzle (bijective: nwg % 8 == 0 for GEMM grids).
__device__ __forceinline__ void swzx(int& bx, int& by) {
    int nx = gridDim.x;
    int nwg = nx * gridDim.y;
    int Lr = blockIdx.y * nx + blockIdx.x;
    int L = (Lr & 7) * (nwg >> 3) + (Lr >> 3);   // contiguous chunk per XCD
    int GSZ = nx * 8;
    int g = L / GSZ, r = L - g * GSZ;
    bx = r % nx;
    by = g * 8 + r / nx;
}

// ---------------- merged: weight converts + u->bf16 + dt projection ----------------
__global__ __launch_bounds__(256) void k_pre2(const float* __restrict__ u, const float* __restrict__ W_in,
                                              const float* __restrict__ dt_bias,
                                              const float* __restrict__ W_out, const float* __restrict__ nw,
                                              bf16* __restrict__ u_b, float* __restrict__ dtt,
                                              bf16* __restrict__ win_b, bf16* __restrict__ wout_b) {
    __shared__ __align__(16) float us[8 * DMODEL];
    const int tid = threadIdx.x;
    if (blockIdx.x < CVTB) {
        int g = (blockIdx.x * 256 + tid) * 4;
        if (g < N1 * DMODEL) {
            f32x4 f = *(const f32x4*)&W_in[g];
            short4_ o;
#pragma unroll
            for (int j = 0; j < 4; j++) o[j] = f2bits(f[j]);
            *(short4_*)&win_b[g] = o;
        } else if (g < N1 * DMODEL + DMODEL * DINNER) {
            int g2 = g - N1 * DMODEL;
            f32x4 f = *(const f32x4*)&W_out[g2];
            f32x4 w = *(const f32x4*)&nw[g2 & (DINNER - 1)];
            short4_ o;
#pragma unroll
            for (int j = 0; j < 4; j++) o[j] = f2bits(f[j] * w[j]);
            *(short4_*)&wout_b[g2] = o;
        }
        return;
    }
    const int t0 = (blockIdx.x - CVTB) * 8;
    const float* ur = u + (size_t)t0 * DMODEL;
    bf16* ub = u_b + (size_t)t0 * DMODEL;
#pragma unroll
    for (int i = 0; i < 8; i++) {
        int idx = (i * 256 + tid) * 4;
        f32x4 v = *(const f32x4*)&ur[idx];
        *(f32x4*)&us[idx] = v;
        short4_ o;
#pragma unroll
        for (int j = 0; j < 4; j++) o[j] = f2bits(v[j]);
        *(short4_*)&ub[idx] = o;
    }
    __syncthreads();
    const int h = tid >> 3, sub = tid & 7;
    const float* wr = W_in + (size_t)(DPROJ - NH + h) * DMODEL;
    float s[8] = {};
    for (int k = sub * 4; k < DMODEL; k += 32) {
        f32x4 w4 = *(const f32x4*)&wr[k];
#pragma unroll
        for (int rr = 0; rr < 8; rr++) {
            f32x4 u4 = *(const f32x4*)&us[rr * DMODEL + k];
            s[rr] += u4[0] * w4[0] + u4[1] * w4[1] + u4[2] * w4[2] + u4[3] * w4[3];
        }
    }
#pragma unroll
    for (int rr = 0; rr < 8; rr++) {
        s[rr] += __shfl_down(s[rr], 4, 8);
        s[rr] += __shfl_down(s[rr], 2, 8);
        s[rr] += __shfl_down(s[rr], 1, 8);
    }
    if (sub == 0) {
        float bh = dt_bias[h];
#pragma unroll
        for (int rr = 0; rr < 8; rr++) {
            float x = s[rr] + bh;
            dtt[(size_t)h * MTOT + t0 + rr] = (x > 20.f) ? x : log1pf(__expf(x));
        }
    }
}

// ---------------- dt chunk-scan precompute ----------------
__global__ __launch_bounds__(256) void k_dts(const float* __restrict__ dtt, const float* __restrict__ A_log,
                                             float* __restrict__ sAc, float* __restrict__ sfv,
                                             float* __restrict__ etot) {
    const int h = blockIdx.x, b = blockIdx.y;
    const int tid = threadIdx.x, w = tid >> 6, lane = tid & 63;
    const float Ah = -__expf(A_log[h]);
#pragma unroll
    for (int g = 0; g < 8; g++) {
        int c = g * 4 + w;
        int t0 = b * SEQ + c * CKL;
        float dv = dtt[(size_t)h * MTOT + t0 + lane];
        float v = Ah * dv;
#pragma unroll
        for (int d = 1; d < 64; d <<= 1) { float o = __shfl_up(v, d); if (lane >= d) v += o; }
        float tot = __shfl(v, 63);
        sAc[(size_t)h * MTOT + t0 + lane] = v;
        sfv[(size_t)h * MTOT + t0 + lane] = __expf(tot - v) * dv;
        if (lane == 63) etot[(h * BSZ + b) * NCH + c] = __expf(tot);
    }
}

// Shared phase scaffolding for the counted-vmcnt GEMMs.
#define BARWAIT()                                           \
    __builtin_amdgcn_s_barrier();                           \
    asm volatile("s_waitcnt lgkmcnt(0)" ::: "memory");      \
    __builtin_amdgcn_sched_barrier(0);                      \
    __builtin_amdgcn_s_setprio(1)
#define ENDPH()                                             \
    __builtin_amdgcn_s_setprio(0);                          \
    __builtin_amdgcn_s_barrier()

// =====================================================================
// GEMM1 (reverted to R7 measured-best): BM=256 x BN=192, BK=64, NT=16.
// 8 waves (2M x 4N), wave 128x48, 2 LDS buffers (112 KiB), 8 phases / 2 K-tiles.
// =====================================================================
__global__ __launch_bounds__(512, 2) void k_g1(const bf16* __restrict__ Ap,
                                               const bf16* __restrict__ Wp,
                                               bf16* __restrict__ Cp) {
    __shared__ __align__(16) short sA[2][16384];  // [buf][256][64]
    __shared__ __align__(16) short sB[2][12288];  // [buf][192][64]
    const int tid = threadIdx.x;
    const int lane = tid & 63, w = tid >> 6;
    const int wm = w >> 2, wn = w & 3;
    const int lr = lane & 15, lk = lane >> 4;
    int bx, by; swzx(bx, by);
    const int m0 = by * 256, n0 = bx * 192;
    const int ld = DMODEL;

    const int r8 = tid >> 3;
    const int c8 = ((tid & 7) ^ (r8 & 7)) * 8;
    const bf16* pA = Ap + (size_t)(m0 + r8) * ld + c8;
    const bf16* pB = Wp + (size_t)(n0 + r8) * ld + c8;

    auto stA = [&](int d, int t) {
#pragma unroll
        for (int h = 0; h < 2; h++)
#pragma unroll
            for (int q = 0; q < 2; q++)
                gl_lds16(pA + (size_t)(h * 128 + q * 64) * ld + t * 64,
                         (bf16*)&sA[d][h * 8192 + q * 4096 + tid * 8]);
    };
    auto stB = [&](int d, int u, int t) {
        gl_lds16(pB + (size_t)(u * 64) * ld + t * 64,
                 (bf16*)&sB[d][u * 4096 + tid * 8]);
    };

    const int c0 = (lk ^ (lr & 7)) * 8;
    const int c1 = ((lk + 4) ^ (lr & 7)) * 8;
    const int aR = (wm * 128 + lr) * 64;
    const int bR = (wn * 48 + lr) * 64;

    f32x4 acc[8][3];
#pragma unroll
    for (int i = 0; i < 8; i++)
#pragma unroll
        for (int j = 0; j < 3; j++) acc[i][j] = (f32x4){0.f, 0.f, 0.f, 0.f};
    short8 bfr[3][2], af[2][2];

#define RDA1(D, I)                                                   \
    af[0][0] = *(const short8*)&sA[D][aR + (I) * 1024 + c0];         \
    af[0][1] = *(const short8*)&sA[D][aR + (I) * 1024 + c1];         \
    af[1][0] = *(const short8*)&sA[D][aR + (I + 1) * 1024 + c0];     \
    af[1][1] = *(const short8*)&sA[D][aR + (I + 1) * 1024 + c1]
#define RDB1(D)                                                      \
    _Pragma("unroll")                                                \
    for (int jn = 0; jn < 3; ++jn) {                                 \
        bfr[jn][0] = *(const short8*)&sB[D][bR + jn * 1024 + c0];    \
        bfr[jn][1] = *(const short8*)&sB[D][bR + jn * 1024 + c1];    \
    }
#define MM1(I)                                                       \
    _Pragma("unroll")                                                \
    for (int hh = 0; hh < 2; ++hh) {                                 \
        _Pragma("unroll")                                            \
        for (int jn = 0; jn < 3; ++jn) {                             \
            acc[I][jn]     = MF(af[0][hh], bfr[jn][hh], acc[I][jn]); \
            acc[I + 1][jn] = MF(af[1][hh], bfr[jn][hh], acc[I + 1][jn]); \
        }                                                            \
    }

    stB(0, 0, 0); stB(0, 1, 0); stB(0, 2, 0); stA(0, 0);
    stB(1, 0, 1); stB(1, 1, 1); stB(1, 2, 1);
    vmw<3>();
    __builtin_amdgcn_s_barrier();

    for (int t0 = 0; t0 < 16; t0 += 2) {
        const int t1 = t0 + 1, t2 = t0 + 2, t3 = t0 + 3;
        const bool more = (t2 < 16);
        // P1
        RDB1(0); RDA1(0, 0);
        stA(1, t1);
        BARWAIT(); MM1(0); ENDPH();
        // P2
        RDA1(0, 2); if (more) stB(0, 0, t2);
        BARWAIT(); MM1(2); ENDPH();
        // P3
        RDA1(0, 4); if (more) stB(0, 1, t2);
        BARWAIT(); MM1(4); ENDPH();
        // P4
        RDA1(0, 6); if (more) stB(0, 2, t2);
        BARWAIT(); MM1(6);
        __builtin_amdgcn_s_setprio(0);
        if (more) vmw<3>(); else vmw<0>();
        __builtin_amdgcn_s_barrier();
        // P5
        RDB1(1); RDA1(1, 0);
        if (more) stA(0, t2);
        BARWAIT(); MM1(0); ENDPH();
        // P6
        RDA1(1, 2); if (more) stB(1, 0, t3);
        BARWAIT(); MM1(2); ENDPH();
        // P7
        RDA1(1, 4); if (more) stB(1, 1, t3);
        BARWAIT(); MM1(4); ENDPH();
        // P8
        RDA1(1, 6); if (more) stB(1, 2, t3);
        BARWAIT(); MM1(6);
        __builtin_amdgcn_s_setprio(0);
        if (more) vmw<3>();
        __builtin_amdgcn_s_barrier();
    }
#undef RDA1
#undef RDB1
#undef MM1

#pragma unroll
    for (int im = 0; im < 8; im++) {
        int row = m0 + wm * 128 + im * 16 + lk * 4;
#pragma unroll
        for (int jn = 0; jn < 3; jn++) {
            int col = n0 + wn * 48 + jn * 16 + lr;
            bf16* cp = Cp + (size_t)row * N1 + col;
#pragma unroll
            for (int rr = 0; rr < 4; rr++) cp[(size_t)rr * N1] = __float2bfloat16(acc[im][jn][rr]);
        }
    }
}

// =====================================================================
// GEMM2 (+fused RMSNorm): out[8192][1024] = A(zx)[8192][2048] * W[1024][2048]^T
// =====================================================================
__global__ __launch_bounds__(512, 2) void k_g2(const bf16* __restrict__ Ap,
                                               const bf16* __restrict__ Wp,
                                               float* __restrict__ Cp) {
    __shared__ __align__(16) short sA[3][16384];  // [buf][256][64]
    __shared__ __align__(16) short sB[3][8192];   // [buf][128][64]
    __shared__ float rsrow[256];
    const int tid = threadIdx.x;
    const int lane = tid & 63, w = tid >> 6;
    const int wm = w >> 1, wn = w & 1;
    const int lr = lane & 15, lk = lane >> 4;
    int bx, by; swzx(bx, by);
    const int m0 = by * 256, n0 = bx * 128;
    const int lda = N1, ldb = DINNER;

    const int r8 = tid >> 3;
    const int c8 = ((tid & 7) ^ (r8 & 7)) * 8;
    const bf16* pA = Ap + (size_t)(m0 + r8) * lda + c8;
    const bf16* pB = Wp + (size_t)(n0 + r8) * ldb + c8;

    auto stA = [&](int d, int t) {
#pragma unroll
        for (int h = 0; h < 2; h++)
#pragma unroll
            for (int q = 0; q < 2; q++)
                gl_lds16(pA + (size_t)(h * 128 + q * 64) * lda + t * 64,
                         (bf16*)&sA[d][h * 8192 + q * 4096 + tid * 8]);
    };
    auto stB = [&](int d, int t) {
#pragma unroll
        for (int q = 0; q < 2; q++)
            gl_lds16(pB + (size_t)(q * 64) * ldb + t * 64,
                     (bf16*)&sB[d][q * 4096 + tid * 8]);
    };

    const int c0 = (lk ^ (lr & 7)) * 8;
    const int c1 = ((lk + 4) ^ (lr & 7)) * 8;
    const int aR = (wm * 64 + lr) * 64;
    const int bR = (wn * 64 + lr) * 64;

    f32x4 acc[4][4];
#pragma unroll
    for (int i = 0; i < 4; i++)
#pragma unroll
        for (int j = 0; j < 4; j++) acc[i][j] = (f32x4){0.f, 0.f, 0.f, 0.f};
    float ssq[4] = {0.f, 0.f, 0.f, 0.f};
    short8 bfr[4][2], af[2][2];

#define RDA2(D, I)                                                   \
    af[0][0] = *(const short8*)&sA[D][aR + (I) * 1024 + c0];         \
    af[0][1] = *(const short8*)&sA[D][aR + (I) * 1024 + c1];         \
    af[1][0] = *(const short8*)&sA[D][aR + (I + 1) * 1024 + c0];     \
    af[1][1] = *(const short8*)&sA[D][aR + (I + 1) * 1024 + c1]
#define RDB2(D)                                                      \
    _Pragma("unroll")                                                \
    for (int jn = 0; jn < 4; ++jn) {                                 \
        bfr[jn][0] = *(const short8*)&sB[D][bR + jn * 1024 + c0];    \
        bfr[jn][1] = *(const short8*)&sB[D][bR + jn * 1024 + c1];    \
    }
#define MM2(I)                                                       \
    _Pragma("unroll")                                                \
    for (int hh = 0; hh < 2; ++hh) {                                 \
        _Pragma("unroll")                                            \
        for (int jn = 0; jn < 4; ++jn) {                             \
            acc[I][jn]     = MF(af[0][hh], bfr[jn][hh], acc[I][jn]); \
            acc[I + 1][jn] = MF(af[1][hh], bfr[jn][hh], acc[I + 1][jn]); \
        }                                                            \
    }
#define SSQ2(I)                                                      \
    _Pragma("unroll")                                                \
    for (int hh = 0; hh < 2; ++hh)                                   \
        _Pragma("unroll")                                            \
        for (int e = 0; e < 8; ++e) {                                \
            float v0 = bits2f(af[0][hh][e]), v1 = bits2f(af[1][hh][e]); \
            ssq[I] += v0 * v0; ssq[I + 1] += v1 * v1;                \
        }

    stB(0, 0); stA(0, 0);
    stB(1, 1); stA(1, 1);
    vmw<6>();
    __builtin_amdgcn_s_barrier();

    int rb = 0, sb = 2;
    for (int t = 0; t < 32; ++t) {
        const bool more = (t + 2 < 32);
        // Pa
        RDB2(rb); RDA2(rb, 0);
        if (more) stB(sb, t + 2);
        BARWAIT(); MM2(0); SSQ2(0); ENDPH();
        // Pb
        RDA2(rb, 2);
        if (more) stA(sb, t + 2);
        BARWAIT(); MM2(2); SSQ2(2);
        __builtin_amdgcn_s_setprio(0);
        if (more) vmw<6>(); else if (t + 1 < 32) vmw<0>();
        __builtin_amdgcn_s_barrier();
        rb = (rb == 2) ? 0 : rb + 1;
        sb = (sb == 2) ? 0 : sb + 1;
    }
#undef RDA2
#undef RDB2
#undef MM2
#undef SSQ2

#pragma unroll
    for (int im = 0; im < 4; im++) {
        float s = ssq[im];
        s += __shfl_down(s, 32);
        s += __shfl_down(s, 16);
        if (lane < 16) rsrow[wm * 64 + im * 16 + lane] = rsqrtf(s * (1.0f / DINNER) + 1e-5f);
    }
    __syncthreads();
#pragma unroll
    for (int im = 0; im < 4; im++) {
        int rl = wm * 64 + im * 16 + lk * 4;
        int row = m0 + rl;
#pragma unroll
        for (int rr = 0; rr < 4; rr++) {
            float s = rsrow[rl + rr];
#pragma unroll
            for (int jn = 0; jn < 4; jn++) {
                int col = n0 + wn * 64 + jn * 16 + lr;
                Cp[(size_t)(row + rr) * DMODEL + col] = acc[im][jn][rr] * s;
            }
        }
    }
}

// ---------------- depthwise causal conv for the B/C columns only ----------------
// x-columns are conv'd inline in k_ssd. 128 cols x 8192 rows, 4 rows x 4 cols/thread.
// xbc_bc layout: [row][0..64)=B, [64..128)=C (post-conv, silu'd).
__global__ __launch_bounds__(256) void k_convbc(const bf16* __restrict__ zx, const float* __restrict__ cw,
                                                const float* __restrict__ cb, bf16* __restrict__ xbc_bc) {
    const int g = blockIdx.x * 256 + threadIdx.x;     // 0 .. 2048*32-1
    const int c0 = (g & 31) * 4;                      // col in [0,128)
    const int t0 = (g >> 5) * 4;
    const int s0 = t0 & (SEQ - 1);
    const short* base = (const short*)(zx + (size_t)t0 * N1 + DINNER + 2048 + c0);
    f32x4 w0 = *(const f32x4*)&cw[(2048 + c0 + 0) * 4];
    f32x4 w1 = *(const f32x4*)&cw[(2048 + c0 + 1) * 4];
    f32x4 w2 = *(const f32x4*)&cw[(2048 + c0 + 2) * 4];
    f32x4 w3 = *(const f32x4*)&cw[(2048 + c0 + 3) * 4];
    f32x4 bias = *(const f32x4*)&cb[2048 + c0];
    short4_ v[7];
#pragma unroll
    for (int o = 0; o < 7; o++) {
        if (s0 + o - 3 >= 0) v[o] = *(const short4_*)(base + (long)(o - 3) * N1);
        else v[o] = (short4_){0, 0, 0, 0};
    }
#pragma unroll
    for (int j = 0; j < 4; j++) {
        f32x4 a = bias;
#pragma unroll
        for (int k = 0; k < 4; k++) {
            short4_ x = v[j + k];
            a[0] += bits2f(x[0]) * w0[k];
            a[1] += bits2f(x[1]) * w1[k];
            a[2] += bits2f(x[2]) * w2[k];
            a[3] += bits2f(x[3]) * w3[k];
        }
        short4_ o_;
#pragma unroll
        for (int jj = 0; jj < 4; jj++) o_[jj] = f2bits(a[jj] * sigmoidf_(a[jj]));
        *(short4_*)((short*)xbc_bc + (size_t)(t0 + j) * 128 + c0) = o_;
    }
}

// ---------------- fused SSD scan (x-conv inlined into the prefetch slot) ----------------
// Each thread owns 8 fixed x-columns: conv weights (8 x f32x4) + bias live in
// registers (loaded once); per chunk the 1 rX load becomes 4 tap loads of zx
// (L3-resident g1 output) + 32 FMA + 8 silu, all in the load_chunk slot that
// overlaps the previous chunk's compute. Removes the conv kernel's x-part
// round-trip (~65 MB traffic + most of a launch).
__global__ __launch_bounds__(256) void k_ssd(const bf16* __restrict__ zx_in, const bf16* __restrict__ xbc_bc,
                                             const float* __restrict__ dtt,
                                             const float* __restrict__ sAc, const float* __restrict__ sfv,
                                             const float* __restrict__ etg, const float* __restrict__ Dp,
                                             const float* __restrict__ cw, const float* __restrict__ cb,
                                             bf16* __restrict__ zx) {
    __shared__ __align__(16) short Ct[2][64 * YSTR];   // C [l][n]; own-wave rows reused as Y [l][p]
    __shared__ __align__(16) short Bt[2][64 * YSTR];   // B [s][n]
    __shared__ __align__(16) short Bn[2][64 * YSTR2];  // (B*sf)^T [n][l], col-shifted
    __shared__ __align__(16) short Xt[2][32 * YSTR2];  // X^T [p][l], col-shifted
    __shared__ __align__(16) short Sb[2][32 * YSTR];   // state bf16 [p][n] at chunk start
    __shared__ __align__(16) short Gs[4 * 16 * YSTR];  // per-wave G
    __shared__ __align__(16) float Sf[32 * 68];        // running state fp32 [p][n]
    __shared__ __align__(16) float sdt2[2][64], sAc2[2][64];
    __shared__ float etl[NCH];

    const int ph = blockIdx.x, h = blockIdx.y, b = blockIdx.z;
    const int tid = threadIdx.x;
    const int lane = tid & 63, w = tid >> 6;
    const int lr = lane & 15, lk = lane >> 4;
    const float Dh = Dp[h];
    const int xcol = h * HD + ph * 32;

    const int lrow = tid >> 2, c0 = (tid & 3) * 16, px = (tid & 3) * 8;
    const int zl = 16 * w + (lane >> 2), zp = (lane & 3) * 8;

    // per-thread x-conv weights for its 8 columns (fixed all kernel)
    f32x4 xw[8]; f32x4 xb0, xb1;
#pragma unroll
    for (int j = 0; j < 8; j++) xw[j] = *(const f32x4*)&cw[(xcol + px + j) * 4];
    xb0 = *(const f32x4*)&cb[xcol + px];
    xb1 = *(const f32x4*)&cb[xcol + px + 4];

    short8 rC0, rC1, rB0, rB1, rX, rZ;
    float rdt, rsa, rsf;
    auto load_chunk = [&](int cc) {
        int rows0 = b * SEQ + cc * CKL;
        const short* rp = (const short*)(xbc_bc + (size_t)(rows0 + lrow) * 128);
        rB0 = *(const short8*)&rp[c0];
        rB1 = *(const short8*)&rp[c0 + 8];
        rC0 = *(const short8*)&rp[64 + c0];
        rC1 = *(const short8*)&rp[64 + c0 + 8];
        // inline causal conv (width 4) + silu for this thread's 8 x-columns
        {
            int rt = rows0 + lrow;
            int s = rt & (SEQ - 1);
            const short* xg = (const short*)zx_in + (size_t)rt * N1 + DINNER + xcol + px;
            short8 tp[4];
#pragma unroll
            for (int k = 0; k < 4; k++) {
                tp[k] = (s + k - 3 >= 0) ? *(const short8*)(xg + (long)(k - 3) * N1)
                                         : (short8){0, 0, 0, 0, 0, 0, 0, 0};
            }
#pragma unroll
            for (int j = 0; j < 8; j++) {
                float a = (j < 4) ? xb0[j] : xb1[j - 4];
#pragma unroll
                for (int k = 0; k < 4; k++) a += bits2f(tp[k][j]) * xw[j][k];
                rX[j] = f2bits(a * sigmoidf_(a));
            }
        }
        rZ  = *(const short8*)((const short*)zx + (size_t)(rows0 + zl) * N1 + xcol + zp);
        rdt = dtt[(size_t)h * MTOT + rows0 + lane];
        rsa = sAc[(size_t)h * MTOT + rows0 + lane];
        rsf = sfv[(size_t)h * MTOT + rows0 + lrow];   // scale for this lane's transpose row
    };
    auto scatter = [&](int buf) {
        *(short8*)&Ct[buf][lrow * YSTR + c0] = rC0;
        *(short8*)&Ct[buf][lrow * YSTR + c0 + 8] = rC1;
        *(short8*)&Bt[buf][lrow * YSTR + c0] = rB0;
        *(short8*)&Bt[buf][lrow * YSTR + c0 + 8] = rB1;
#pragma unroll
        for (int j = 0; j < 8; j++) {
            int n0_ = c0 + j, n1_ = c0 + 8 + j, p_ = px + j;
            Bn[buf][n0_ * YSTR2 + lrow + (n0_ >> 3) * 8] = f2bits(bits2f(rB0[j]) * rsf);
            Bn[buf][n1_ * YSTR2 + lrow + (n1_ >> 3) * 8] = f2bits(bits2f(rB1[j]) * rsf);
            Xt[buf][p_ * YSTR2 + lrow + (p_ >> 3) * 8] = rX[j];
        }
        if (tid < 64) { sdt2[buf][tid] = rdt; sAc2[buf][tid] = rsa; }
    };

    for (int i = tid; i < 32 * 68; i += 256) Sf[i] = 0.f;
    for (int i = tid; i < 32 * YSTR; i += 256) Sb[0][i] = 0;
    if (tid < NCH) etl[tid] = etg[(h * BSZ + b) * NCH + tid];
    load_chunk(0);
    scatter(0);
    __syncthreads();

    for (int c = 0; c < NCH; c++) {
        const int par = c & 1, nb = par ^ 1;
        const int rows0 = b * SEQ + c * CKL;
        float etot = etl[c];
        short8 zcur = rZ;                 // z of chunk c (loaded last iteration / pre-loop)
        if (c + 1 < NCH) load_chunk(c + 1);

        short8 cf0 = *(const short8*)&Ct[par][(16 * w + lr) * YSTR + lk * 8];
        short8 cf1 = *(const short8*)&Ct[par][(16 * w + lr) * YSTR + 32 + lk * 8];
        // P1: Y_off = C * S0^T
        f32x4 acc[2];
#pragma unroll
        for (int t = 0; t < 2; t++) {
            short8 s0 = *(const short8*)&Sb[par][(16 * t + lr) * YSTR + lk * 8];
            short8 s1 = *(const short8*)&Sb[par][(16 * t + lr) * YSTR + 32 + lk * 8];
            acc[t] = MF(cf0, s0, (f32x4){0.f, 0.f, 0.f, 0.f});
            acc[t] = MF(cf1, s1, acc[t]);
        }
        float sAcl[4], el[4];
#pragma unroll
        for (int rr = 0; rr < 4; rr++) { sAcl[rr] = sAc2[par][16 * w + lk * 4 + rr]; el[rr] = __expf(sAcl[rr]); }
#pragma unroll
        for (int t = 0; t < 2; t++)
#pragma unroll
            for (int rr = 0; rr < 4; rr++) acc[t][rr] *= el[rr];
        // P2: G = C * B^T, mask/decay, wave-private LDS round-trip
        short* gw = Gs + w * 16 * YSTR;
#pragma unroll
        for (int t = 0; t < 4; t++) {
            short8 b0 = *(const short8*)&Bt[par][(16 * t + lr) * YSTR + lk * 8];
            short8 b1 = *(const short8*)&Bt[par][(16 * t + lr) * YSTR + 32 + lk * 8];
            f32x4 g = MF(cf0, b0, (f32x4){0.f, 0.f, 0.f, 0.f});
            g = MF(cf1, b1, g);
            int s = 16 * t + lr;
            float sAcs = sAc2[par][s], dts = sdt2[par][s];
#pragma unroll
            for (int rr = 0; rr < 4; rr++) {
                int l = 16 * w + lk * 4 + rr;
                float v = (s <= l) ? g[rr] * __expf(sAcl[rr] - sAcs) * dts : 0.f;
                gw[(lk * 4 + rr) * YSTR + s] = f2bits(v);
            }
        }
        // P3: Y += G * X
        short8 gf0 = *(const short8*)&gw[lr * YSTR + lk * 8];
        short8 gf1 = *(const short8*)&gw[lr * YSTR + 32 + lk * 8];
#pragma unroll
        for (int t = 0; t < 2; t++) {
            int xr = 16 * t + lr;
            short8 x0 = *(const short8*)&Xt[par][xr * YSTR2 + ((xr >> 3) + lk) * 8];
            short8 x1 = *(const short8*)&Xt[par][xr * YSTR2 + 32 + ((xr >> 3) + lk) * 8];
            acc[t] = MF(gf0, x0, acc[t]);
            acc[t] = MF(gf1, x1, acc[t]);
        }
        // P4: Snew = X * (B*sf)^T ; Sf = Sf*etot + Snew ; Sb[nb] = bf16(Sf)
        {
            int pw = w & 1, nh2 = w >> 1;
            const int xp = 16 * pw + lr;
            short8 xt0 = *(const short8*)&Xt[par][xp * YSTR2 + ((xp >> 3) + lk) * 8];
            short8 xt1 = *(const short8*)&Xt[par][xp * YSTR2 + 32 + ((xp >> 3) + lk) * 8];
#pragma unroll
            for (int j = 0; j < 2; j++) {
                int nt = 2 * nh2 + j;
                int nr = 16 * nt + lr;
                short8 b0 = *(const short8*)&Bn[par][nr * YSTR2 + ((nr >> 3) + lk) * 8];
                short8 b1 = *(const short8*)&Bn[par][nr * YSTR2 + 32 + ((nr >> 3) + lk) * 8];
                f32x4 sacc = MF(xt0, b0, (f32x4){0.f, 0.f, 0.f, 0.f});
                sacc = MF(xt1, b1, sacc);
#pragma unroll
                for (int rr = 0; rr < 4; rr++) {
                    int n = 16 * nt + lr;
                    int p = 16 * pw + lk * 4 + rr;
                    float nv = Sf[p * 68 + n] * etot + sacc[rr];
                    Sf[p * 68 + n] = nv;
                    Sb[nb][p * YSTR + n] = f2bits(nv);
                }
            }
        }
        // Y epilogue (+D*x) into Ct[par]'s own wave rows; coalesced z-gate
#pragma unroll
        for (int t = 0; t < 2; t++) {
#pragma unroll
            for (int rr = 0; rr < 4; rr++) {
                int p = 16 * t + lr;
                int l = 16 * w + lk * 4 + rr;
                float y = acc[t][rr] + Dh * bits2f(Xt[par][p * YSTR2 + l + (p >> 3) * 8]);
                Ct[par][l * YSTR + p] = f2bits(y);
            }
        }
        {
            short8 y8 = *(const short8*)&Ct[par][zl * YSTR + zp];
            short* zpp = (short*)zx + (size_t)(rows0 + zl) * N1 + xcol + zp;
            short8 o;
#pragma unroll
            for (int j = 0; j < 8; j++) {
                float z = bits2f(zcur[j]);
                o[j] = f2bits(bits2f(y8[j]) * (z * sigmoidf_(z)));
            }
            *(short8*)zpp = o;
        }
        // stage chunk c+1 (off critical path: independent of this chunk's compute)
        if (c + 1 < NCH) {
            scatter(nb);
        }
        __syncthreads();
    }
}

extern "C" void kernel_launch(void* const* d_in, const int* in_sizes, int n_in,
                              void* d_out, int out_size, void* d_ws, size_t ws_size,
                              hipStream_t stream) {
    const float* u       = (const float*)d_in[0];
    const float* W_in    = (const float*)d_in[1];
    const float* conv_w  = (const float*)d_in[2];
    const float* conv_b  = (const float*)d_in[3];
    const float* dt_bias = (const float*)d_in[4];
    const float* A_log   = (const float*)d_in[5];
    const float* Dp      = (const float*)d_in[6];
    const float* norm_w  = (const float*)d_in[7];
    const float* W_out   = (const float*)d_in[8];
    float* out = (float*)d_out;

    // Workspace layout (~80 MiB total):
    char* ws = (char*)d_ws;
    bf16* zx     = (bf16*)ws;  ws += (size_t)MTOT * N1 * 2;       // 69.2 MB
    bf16* xbc_bc = (bf16*)ws;  ws += (size_t)MTOT * 128 * 2;      // 2 MB (B/C post-conv only)
    bf16* wout_b = (bf16*)ws;  ws += (size_t)DMODEL * DINNER * 2; // 4 MB
    float* dtt   = (float*)ws; ws += (size_t)NH * MTOT * 4;       // 1 MB, [h][t]
    float* sAcw  = (float*)ws; ws += (size_t)NH * MTOT * 4;       // 1 MB
    float* sfvw  = (float*)ws; ws += (size_t)NH * MTOT * 4;       // 1 MB
    float* etotw = (float*)ws; ws += 64 * 1024;                   // 16 KB (padded)

    // d_out (32 MiB) doubles as scratch for GEMM1 inputs only.
    bf16* u_b   = (bf16*)d_out;                                      // 16 MB
    bf16* win_b = (bf16*)((char*)d_out + (size_t)MTOT * DMODEL * 2); // 8.25 MB

    // merged weight-convert + u-prep + dt projection (one launch)
    k_pre2<<<CVTB + MTOT / 8, 256, 0, stream>>>(u, W_in, dt_bias, W_out, norm_w,
                                                u_b, dtt, win_b, wout_b);
    // dt chunk-scan precompute
    k_dts<<<dim3(NH, BSZ), 256, 0, stream>>>(dtt, A_log, sAcw, sfvw, etotw);

    // GEMM1: 256x192 tiles, 8-phase counted-vmcnt pipeline (measured-best R7 version)
    k_g1<<<dim3(N1 / 192, MTOT / 256), 512, 0, stream>>>(u_b, win_b, zx);

    // depthwise conv for B/C columns only (x is conv'd inline in k_ssd)
    k_convbc<<<(MTOT / 4) * (128 / 4) / 256, 256, 0, stream>>>(zx, conv_w, conv_b, xbc_bc);

    // fused SSD scan with inline x-conv
    k_ssd<<<dim3(2, NH, BSZ), 256, 0, stream>>>(zx, xbc_bc, dtt, sAcw, sfvw, etotw, Dp,
                                                conv_w, conv_b, zx);

    // GEMM2 (+RMS): 256x128 tiles, 3-buffer counted-vmcnt pipeline, zero tail
    k_g2<<<dim3(DMODEL / 128, MTOT / 256), 512, 0, stream>>>(zx, wout_b, out);
}

// Round 10
// 350.494 us; speedup vs baseline: 1.1006x; 1.1006x over previous
//
#include <hip/hip_runtime.h>
#include <hip/hip_bf16.h>

#define BSZ 4
#define SEQ 2048
#define DMODEL 1024
#define DINNER 2048
#define DSTATE 64
#define NH 32
#define HD 64
#define CKL 64            // chunk length
#define NCH 32            // chunks per sequence
#define CONVD 2176
#define DPROJ 4256
#define N1 4224           // GEMM1 N = DINNER + CONVD = 22*192
#define MTOT 8192         // BSZ*SEQ
#define YSTR 72           // LDS row stride (bf16): 144 B = 36 dwords (== 4 mod 32: b128 reads conflict-free)
#define YSTR2 120         // transpose arrays: 240 B = 60 dwords (== 28 mod 32) + 8*(row>>3) column shift
#define CVTB 6272         // blocks of k_pre2 doing weight-convert role

typedef __hip_bfloat16 bf16;
typedef __attribute__((ext_vector_type(8))) short short8;   // 8 bf16 (4 VGPRs)
typedef __attribute__((ext_vector_type(4))) short short4_;  // 8 bytes
typedef __attribute__((ext_vector_type(4))) float f32x4;

__device__ __forceinline__ float sigmoidf_(float x) { return 1.0f / (1.0f + __expf(-x)); }
__device__ __forceinline__ float bits2f(short s) { return __uint_as_float(((unsigned)(unsigned short)s) << 16); }
__device__ __forceinline__ short f2bits(float f) {
    bf16 h = __float2bfloat16(f);
    return *reinterpret_cast<short*>(&h);
}

__device__ __forceinline__ void gl_lds16(const bf16* g, bf16* l) {
    __builtin_amdgcn_global_load_lds((const __attribute__((address_space(1))) void*)g,
                                     (__attribute__((address_space(3))) void*)l, 16, 0, 0);
}

__device__ __forceinline__ f32x4 MF(short8 a, short8 b, f32x4 c) {
    return __builtin_amdgcn_mfma_f32_16x16x32_bf16(a, b, c, 0, 0, 0);
}

// counted s_waitcnt vmcnt(N); "memory" clobber = compiler fence.
template<int N> __device__ __forceinline__ void vmw() {
    if constexpr (N == 0)      asm volatile("s_waitcnt vmcnt(0)" ::: "memory");
    else if constexpr (N == 3) asm volatile("s_waitcnt vmcnt(3)" ::: "memory");
    else if constexpr (N == 6) asm volatile("s_waitcnt vmcnt(6)" ::: "memory");
    else                       asm volatile("s_waitcnt vmcnt(15)" ::: "memory");
}

// XCD-chunked locality swizzle (bijective: nwg % 8 == 0 for GEMM grids).
__device__ __forceinline__ void swzx(int& bx, int& by) {
    int nx = gridDim.x;
    int nwg = nx * gridDim.y;
    int Lr = blockIdx.y * nx + blockIdx.x;
    int L = (Lr & 7) * (nwg >> 3) + (Lr >> 3);   // contiguous chunk per XCD
    int GSZ = nx * 8;
    int g = L / GSZ, r = L - g * GSZ;
    bx = r % nx;
    by = g * 8 + r / nx;
}

// ---------------- merged: weight converts + u->bf16 + dt projection ----------------
__global__ __launch_bounds__(256) void k_pre2(const float* __restrict__ u, const float* __restrict__ W_in,
                                              const float* __restrict__ dt_bias,
                                              const float* __restrict__ W_out, const float* __restrict__ nw,
                                              bf16* __restrict__ u_b, float* __restrict__ dtt,
                                              bf16* __restrict__ win_b, bf16* __restrict__ wout_b) {
    __shared__ __align__(16) float us[8 * DMODEL];
    const int tid = threadIdx.x;
    if (blockIdx.x < CVTB) {
        int g = (blockIdx.x * 256 + tid) * 4;
        if (g < N1 * DMODEL) {
            f32x4 f = *(const f32x4*)&W_in[g];
            short4_ o;
#pragma unroll
            for (int j = 0; j < 4; j++) o[j] = f2bits(f[j]);
            *(short4_*)&win_b[g] = o;
        } else if (g < N1 * DMODEL + DMODEL * DINNER) {
            int g2 = g - N1 * DMODEL;
            f32x4 f = *(const f32x4*)&W_out[g2];
            f32x4 w = *(const f32x4*)&nw[g2 & (DINNER - 1)];
            short4_ o;
#pragma unroll
            for (int j = 0; j < 4; j++) o[j] = f2bits(f[j] * w[j]);
            *(short4_*)&wout_b[g2] = o;
        }
        return;
    }
    const int t0 = (blockIdx.x - CVTB) * 8;
    const float* ur = u + (size_t)t0 * DMODEL;
    bf16* ub = u_b + (size_t)t0 * DMODEL;
#pragma unroll
    for (int i = 0; i < 8; i++) {
        int idx = (i * 256 + tid) * 4;
        f32x4 v = *(const f32x4*)&ur[idx];
        *(f32x4*)&us[idx] = v;
        short4_ o;
#pragma unroll
        for (int j = 0; j < 4; j++) o[j] = f2bits(v[j]);
        *(short4_*)&ub[idx] = o;
    }
    __syncthreads();
    const int h = tid >> 3, sub = tid & 7;
    const float* wr = W_in + (size_t)(DPROJ - NH + h) * DMODEL;
    float s[8] = {};
    for (int k = sub * 4; k < DMODEL; k += 32) {
        f32x4 w4 = *(const f32x4*)&wr[k];
#pragma unroll
        for (int rr = 0; rr < 8; rr++) {
            f32x4 u4 = *(const f32x4*)&us[rr * DMODEL + k];
            s[rr] += u4[0] * w4[0] + u4[1] * w4[1] + u4[2] * w4[2] + u4[3] * w4[3];
        }
    }
#pragma unroll
    for (int rr = 0; rr < 8; rr++) {
        s[rr] += __shfl_down(s[rr], 4, 8);
        s[rr] += __shfl_down(s[rr], 2, 8);
        s[rr] += __shfl_down(s[rr], 1, 8);
    }
    if (sub == 0) {
        float bh = dt_bias[h];
#pragma unroll
        for (int rr = 0; rr < 8; rr++) {
            float x = s[rr] + bh;
            dtt[(size_t)h * MTOT + t0 + rr] = (x > 20.f) ? x : log1pf(__expf(x));
        }
    }
}

// ---------------- dt chunk-scan precompute ----------------
__global__ __launch_bounds__(256) void k_dts(const float* __restrict__ dtt, const float* __restrict__ A_log,
                                             float* __restrict__ sAc, float* __restrict__ sfv,
                                             float* __restrict__ etot) {
    const int h = blockIdx.x, b = blockIdx.y;
    const int tid = threadIdx.x, w = tid >> 6, lane = tid & 63;
    const float Ah = -__expf(A_log[h]);
#pragma unroll
    for (int g = 0; g < 8; g++) {
        int c = g * 4 + w;
        int t0 = b * SEQ + c * CKL;
        float dv = dtt[(size_t)h * MTOT + t0 + lane];
        float v = Ah * dv;
#pragma unroll
        for (int d = 1; d < 64; d <<= 1) { float o = __shfl_up(v, d); if (lane >= d) v += o; }
        float tot = __shfl(v, 63);
        sAc[(size_t)h * MTOT + t0 + lane] = v;
        sfv[(size_t)h * MTOT + t0 + lane] = __expf(tot - v) * dv;
        if (lane == 63) etot[(h * BSZ + b) * NCH + c] = __expf(tot);
    }
}

// Shared phase scaffolding for the counted-vmcnt GEMMs.
#define BARWAIT()                                           \
    __builtin_amdgcn_s_barrier();                           \
    asm volatile("s_waitcnt lgkmcnt(0)" ::: "memory");      \
    __builtin_amdgcn_sched_barrier(0);                      \
    __builtin_amdgcn_s_setprio(1)
#define ENDPH()                                             \
    __builtin_amdgcn_s_setprio(0);                          \
    __builtin_amdgcn_s_barrier()

// =====================================================================
// GEMM1 (R7 measured-best): BM=256 x BN=192, BK=64, NT=16.
// =====================================================================
__global__ __launch_bounds__(512, 2) void k_g1(const bf16* __restrict__ Ap,
                                               const bf16* __restrict__ Wp,
                                               bf16* __restrict__ Cp) {
    __shared__ __align__(16) short sA[2][16384];  // [buf][256][64]
    __shared__ __align__(16) short sB[2][12288];  // [buf][192][64]
    const int tid = threadIdx.x;
    const int lane = tid & 63, w = tid >> 6;
    const int wm = w >> 2, wn = w & 3;
    const int lr = lane & 15, lk = lane >> 4;
    int bx, by; swzx(bx, by);
    const int m0 = by * 256, n0 = bx * 192;
    const int ld = DMODEL;

    const int r8 = tid >> 3;
    const int c8 = ((tid & 7) ^ (r8 & 7)) * 8;
    const bf16* pA = Ap + (size_t)(m0 + r8) * ld + c8;
    const bf16* pB = Wp + (size_t)(n0 + r8) * ld + c8;

    auto stA = [&](int d, int t) {
#pragma unroll
        for (int h = 0; h < 2; h++)
#pragma unroll
            for (int q = 0; q < 2; q++)
                gl_lds16(pA + (size_t)(h * 128 + q * 64) * ld + t * 64,
                         (bf16*)&sA[d][h * 8192 + q * 4096 + tid * 8]);
    };
    auto stB = [&](int d, int u, int t) {
        gl_lds16(pB + (size_t)(u * 64) * ld + t * 64,
                 (bf16*)&sB[d][u * 4096 + tid * 8]);
    };

    const int c0 = (lk ^ (lr & 7)) * 8;
    const int c1 = ((lk + 4) ^ (lr & 7)) * 8;
    const int aR = (wm * 128 + lr) * 64;
    const int bR = (wn * 48 + lr) * 64;

    f32x4 acc[8][3];
#pragma unroll
    for (int i = 0; i < 8; i++)
#pragma unroll
        for (int j = 0; j < 3; j++) acc[i][j] = (f32x4){0.f, 0.f, 0.f, 0.f};
    short8 bfr[3][2], af[2][2];

#define RDA1(D, I)                                                   \
    af[0][0] = *(const short8*)&sA[D][aR + (I) * 1024 + c0];         \
    af[0][1] = *(const short8*)&sA[D][aR + (I) * 1024 + c1];         \
    af[1][0] = *(const short8*)&sA[D][aR + (I + 1) * 1024 + c0];     \
    af[1][1] = *(const short8*)&sA[D][aR + (I + 1) * 1024 + c1]
#define RDB1(D)                                                      \
    _Pragma("unroll")                                                \
    for (int jn = 0; jn < 3; ++jn) {                                 \
        bfr[jn][0] = *(const short8*)&sB[D][bR + jn * 1024 + c0];    \
        bfr[jn][1] = *(const short8*)&sB[D][bR + jn * 1024 + c1];    \
    }
#define MM1(I)                                                       \
    _Pragma("unroll")                                                \
    for (int hh = 0; hh < 2; ++hh) {                                 \
        _Pragma("unroll")                                            \
        for (int jn = 0; jn < 3; ++jn) {                             \
            acc[I][jn]     = MF(af[0][hh], bfr[jn][hh], acc[I][jn]); \
            acc[I + 1][jn] = MF(af[1][hh], bfr[jn][hh], acc[I + 1][jn]); \
        }                                                            \
    }

    stB(0, 0, 0); stB(0, 1, 0); stB(0, 2, 0); stA(0, 0);
    stB(1, 0, 1); stB(1, 1, 1); stB(1, 2, 1);
    vmw<3>();
    __builtin_amdgcn_s_barrier();

    for (int t0 = 0; t0 < 16; t0 += 2) {
        const int t1 = t0 + 1, t2 = t0 + 2, t3 = t0 + 3;
        const bool more = (t2 < 16);
        // P1
        RDB1(0); RDA1(0, 0);
        stA(1, t1);
        BARWAIT(); MM1(0); ENDPH();
        // P2
        RDA1(0, 2); if (more) stB(0, 0, t2);
        BARWAIT(); MM1(2); ENDPH();
        // P3
        RDA1(0, 4); if (more) stB(0, 1, t2);
        BARWAIT(); MM1(4); ENDPH();
        // P4
        RDA1(0, 6); if (more) stB(0, 2, t2);
        BARWAIT(); MM1(6);
        __builtin_amdgcn_s_setprio(0);
        if (more) vmw<3>(); else vmw<0>();
        __builtin_amdgcn_s_barrier();
        // P5
        RDB1(1); RDA1(1, 0);
        if (more) stA(0, t2);
        BARWAIT(); MM1(0); ENDPH();
        // P6
        RDA1(1, 2); if (more) stB(1, 0, t3);
        BARWAIT(); MM1(2); ENDPH();
        // P7
        RDA1(1, 4); if (more) stB(1, 1, t3);
        BARWAIT(); MM1(4); ENDPH();
        // P8
        RDA1(1, 6); if (more) stB(1, 2, t3);
        BARWAIT(); MM1(6);
        __builtin_amdgcn_s_setprio(0);
        if (more) vmw<3>();
        __builtin_amdgcn_s_barrier();
    }
#undef RDA1
#undef RDB1
#undef MM1

#pragma unroll
    for (int im = 0; im < 8; im++) {
        int row = m0 + wm * 128 + im * 16 + lk * 4;
#pragma unroll
        for (int jn = 0; jn < 3; jn++) {
            int col = n0 + wn * 48 + jn * 16 + lr;
            bf16* cp = Cp + (size_t)row * N1 + col;
#pragma unroll
            for (int rr = 0; rr < 4; rr++) cp[(size_t)rr * N1] = __float2bfloat16(acc[im][jn][rr]);
        }
    }
}

// =====================================================================
// GEMM2 (+fused RMSNorm): out[8192][1024] = A(zx)[8192][2048] * W[1024][2048]^T
// =====================================================================
__global__ __launch_bounds__(512, 2) void k_g2(const bf16* __restrict__ Ap,
                                               const bf16* __restrict__ Wp,
                                               float* __restrict__ Cp) {
    __shared__ __align__(16) short sA[3][16384];  // [buf][256][64]
    __shared__ __align__(16) short sB[3][8192];   // [buf][128][64]
    __shared__ float rsrow[256];
    const int tid = threadIdx.x;
    const int lane = tid & 63, w = tid >> 6;
    const int wm = w >> 1, wn = w & 1;
    const int lr = lane & 15, lk = lane >> 4;
    int bx, by; swzx(bx, by);
    const int m0 = by * 256, n0 = bx * 128;
    const int lda = N1, ldb = DINNER;

    const int r8 = tid >> 3;
    const int c8 = ((tid & 7) ^ (r8 & 7)) * 8;
    const bf16* pA = Ap + (size_t)(m0 + r8) * lda + c8;
    const bf16* pB = Wp + (size_t)(n0 + r8) * ldb + c8;

    auto stA = [&](int d, int t) {
#pragma unroll
        for (int h = 0; h < 2; h++)
#pragma unroll
            for (int q = 0; q < 2; q++)
                gl_lds16(pA + (size_t)(h * 128 + q * 64) * lda + t * 64,
                         (bf16*)&sA[d][h * 8192 + q * 4096 + tid * 8]);
    };
    auto stB = [&](int d, int t) {
#pragma unroll
        for (int q = 0; q < 2; q++)
            gl_lds16(pB + (size_t)(q * 64) * ldb + t * 64,
                     (bf16*)&sB[d][q * 4096 + tid * 8]);
    };

    const int c0 = (lk ^ (lr & 7)) * 8;
    const int c1 = ((lk + 4) ^ (lr & 7)) * 8;
    const int aR = (wm * 64 + lr) * 64;
    const int bR = (wn * 64 + lr) * 64;

    f32x4 acc[4][4];
#pragma unroll
    for (int i = 0; i < 4; i++)
#pragma unroll
        for (int j = 0; j < 4; j++) acc[i][j] = (f32x4){0.f, 0.f, 0.f, 0.f};
    float ssq[4] = {0.f, 0.f, 0.f, 0.f};
    short8 bfr[4][2], af[2][2];

#define RDA2(D, I)                                                   \
    af[0][0] = *(const short8*)&sA[D][aR + (I) * 1024 + c0];         \
    af[0][1] = *(const short8*)&sA[D][aR + (I) * 1024 + c1];         \
    af[1][0] = *(const short8*)&sA[D][aR + (I + 1) * 1024 + c0];     \
    af[1][1] = *(const short8*)&sA[D][aR + (I + 1) * 1024 + c1]
#define RDB2(D)                                                      \
    _Pragma("unroll")                                                \
    for (int jn = 0; jn < 4; ++jn) {                                 \
        bfr[jn][0] = *(const short8*)&sB[D][bR + jn * 1024 + c0];    \
        bfr[jn][1] = *(const short8*)&sB[D][bR + jn * 1024 + c1];    \
    }
#define MM2(I)                                                       \
    _Pragma("unroll")                                                \
    for (int hh = 0; hh < 2; ++hh) {                                 \
        _Pragma("unroll")                                            \
        for (int jn = 0; jn < 4; ++jn) {                             \
            acc[I][jn]     = MF(af[0][hh], bfr[jn][hh], acc[I][jn]); \
            acc[I + 1][jn] = MF(af[1][hh], bfr[jn][hh], acc[I + 1][jn]); \
        }                                                            \
    }
#define SSQ2(I)                                                      \
    _Pragma("unroll")                                                \
    for (int hh = 0; hh < 2; ++hh)                                   \
        _Pragma("unroll")                                            \
        for (int e = 0; e < 8; ++e) {                                \
            float v0 = bits2f(af[0][hh][e]), v1 = bits2f(af[1][hh][e]); \
            ssq[I] += v0 * v0; ssq[I + 1] += v1 * v1;                \
        }

    stB(0, 0); stA(0, 0);
    stB(1, 1); stA(1, 1);
    vmw<6>();
    __builtin_amdgcn_s_barrier();

    int rb = 0, sb = 2;
    for (int t = 0; t < 32; ++t) {
        const bool more = (t + 2 < 32);
        // Pa
        RDB2(rb); RDA2(rb, 0);
        if (more) stB(sb, t + 2);
        BARWAIT(); MM2(0); SSQ2(0); ENDPH();
        // Pb
        RDA2(rb, 2);
        if (more) stA(sb, t + 2);
        BARWAIT(); MM2(2); SSQ2(2);
        __builtin_amdgcn_s_setprio(0);
        if (more) vmw<6>(); else if (t + 1 < 32) vmw<0>();
        __builtin_amdgcn_s_barrier();
        rb = (rb == 2) ? 0 : rb + 1;
        sb = (sb == 2) ? 0 : sb + 1;
    }
#undef RDA2
#undef RDB2
#undef MM2
#undef SSQ2

#pragma unroll
    for (int im = 0; im < 4; im++) {
        float s = ssq[im];
        s += __shfl_down(s, 32);
        s += __shfl_down(s, 16);
        if (lane < 16) rsrow[wm * 64 + im * 16 + lane] = rsqrtf(s * (1.0f / DINNER) + 1e-5f);
    }
    __syncthreads();
#pragma unroll
    for (int im = 0; im < 4; im++) {
        int rl = wm * 64 + im * 16 + lk * 4;
        int row = m0 + rl;
#pragma unroll
        for (int rr = 0; rr < 4; rr++) {
            float s = rsrow[rl + rr];
#pragma unroll
            for (int jn = 0; jn < 4; jn++) {
                int col = n0 + wn * 64 + jn * 16 + lr;
                Cp[(size_t)(row + rr) * DMODEL + col] = acc[im][jn][rr] * s;
            }
        }
    }
}

// ---------------- depthwise causal conv (width 4) + bias + SiLU ----------------
// 4 rows x 4 channels per thread (R6 measured-best version).
__global__ __launch_bounds__(256) void k_conv(const bf16* __restrict__ zx, const float* __restrict__ cw,
                                              const float* __restrict__ cb, bf16* __restrict__ xbc) {
    const int g = blockIdx.x * 256 + threadIdx.x;     // 0 .. 2048*544-1
    const int c0 = (g % 544) * 4;
    const int t0 = (g / 544) * 4;
    const int s0 = t0 & (SEQ - 1);
    const short* base = (const short*)(zx + (size_t)t0 * N1 + DINNER + c0);
    f32x4 w0 = *(const f32x4*)&cw[(c0 + 0) * 4];
    f32x4 w1 = *(const f32x4*)&cw[(c0 + 1) * 4];
    f32x4 w2 = *(const f32x4*)&cw[(c0 + 2) * 4];
    f32x4 w3 = *(const f32x4*)&cw[(c0 + 3) * 4];
    f32x4 bias = *(const f32x4*)&cb[c0];
    short4_ v[7];
#pragma unroll
    for (int o = 0; o < 7; o++) {
        if (s0 + o - 3 >= 0) v[o] = *(const short4_*)(base + (long)(o - 3) * N1);
        else v[o] = (short4_){0, 0, 0, 0};
    }
#pragma unroll
    for (int j = 0; j < 4; j++) {
        f32x4 a = bias;
#pragma unroll
        for (int k = 0; k < 4; k++) {
            short4_ x = v[j + k];
            a[0] += bits2f(x[0]) * w0[k];
            a[1] += bits2f(x[1]) * w1[k];
            a[2] += bits2f(x[2]) * w2[k];
            a[3] += bits2f(x[3]) * w3[k];
        }
        short4_ o_;
#pragma unroll
        for (int jj = 0; jj < 4; jj++) o_[jj] = f2bits(a[jj] * sigmoidf_(a[jj]));
        *(short4_*)((short*)xbc + (size_t)(t0 + j) * CONVD + c0) = o_;
    }
}

// ---------------- fused SSD scan: producer/consumer wave split ----------------
// 512 threads: waves 0-3 (consumers) run the serial chunk compute (P1..P4 +
// epilogue + z-gate) and own the state (Sf/Sb). Waves 4-7 (producers) load
// chunk c+1 from global and scatter it into buf nb CONCURRENTLY with chunk c's
// compute -- removing the load-issue + 28-LDS-write scatter from the serial
// chain and giving 2 waves/SIMD of latency overlap. Buffer tenancy: buf nb's
// last readers finished before the c-1 -> c barrier (same invariant as the
// old same-thread scatter); one barrier per chunk, unchanged.
__global__ __launch_bounds__(512) void k_ssd(const bf16* __restrict__ xbc, const float* __restrict__ dtt,
                                             const float* __restrict__ sAc, const float* __restrict__ sfv,
                                             const float* __restrict__ etg, const float* __restrict__ Dp,
                                             bf16* __restrict__ zx) {
    __shared__ __align__(16) short Ct[2][64 * YSTR];   // C [l][n]; own-wave rows reused as Y [l][p]
    __shared__ __align__(16) short Bt[2][64 * YSTR];   // B [s][n]
    __shared__ __align__(16) short Bn[2][64 * YSTR2];  // (B*sf)^T [n][l], col-shifted
    __shared__ __align__(16) short Xt[2][32 * YSTR2];  // X^T [p][l], col-shifted
    __shared__ __align__(16) short Sb[2][32 * YSTR];   // state bf16 [p][n] at chunk start
    __shared__ __align__(16) short Gs[4 * 16 * YSTR];  // per-wave G (consumer waves)
    __shared__ __align__(16) float Sf[32 * 68];        // running state fp32 [p][n]
    __shared__ __align__(16) float sdt2[2][64], sAc2[2][64];
    __shared__ float etl[NCH];

    const int ph = blockIdx.x, h = blockIdx.y, b = blockIdx.z;
    const int tid = threadIdx.x;
    const bool prod = tid >= 256;
    const int ct = tid & 255;                 // role-local id
    const int lane = ct & 63, w = ct >> 6;    // consumer wave 0..3
    const int lr = lane & 15, lk = lane >> 4;
    const float Dh = Dp[h];
    const int xcol = h * HD + ph * 32;

    // producer mapping
    const int lrow = ct >> 2, c0 = (ct & 3) * 16, px = (ct & 3) * 8;
    // consumer z mapping
    const int zl = 16 * w + (lane >> 2), zp = (lane & 3) * 8;

    short8 rC0, rC1, rB0, rB1, rX;
    float rdt, rsa, rsf;
    auto load_chunk = [&](int cc) {           // producer-only
        int rows0 = b * SEQ + cc * CKL;
        const short* rp = (const short*)(xbc + (size_t)(rows0 + lrow) * CONVD);
        rC0 = *(const short8*)&rp[DINNER + DSTATE + c0];
        rC1 = *(const short8*)&rp[DINNER + DSTATE + c0 + 8];
        rB0 = *(const short8*)&rp[DINNER + c0];
        rB1 = *(const short8*)&rp[DINNER + c0 + 8];
        rX  = *(const short8*)&rp[xcol + px];
        rdt = dtt[(size_t)h * MTOT + rows0 + (ct & 63)];
        rsa = sAc[(size_t)h * MTOT + rows0 + (ct & 63)];
        rsf = sfv[(size_t)h * MTOT + rows0 + lrow];
    };
    auto scatter = [&](int buf) {             // producer-only
        *(short8*)&Ct[buf][lrow * YSTR + c0] = rC0;
        *(short8*)&Ct[buf][lrow * YSTR + c0 + 8] = rC1;
        *(short8*)&Bt[buf][lrow * YSTR + c0] = rB0;
        *(short8*)&Bt[buf][lrow * YSTR + c0 + 8] = rB1;
#pragma unroll
        for (int j = 0; j < 8; j++) {
            int n0_ = c0 + j, n1_ = c0 + 8 + j, p_ = px + j;
            Bn[buf][n0_ * YSTR2 + lrow + (n0_ >> 3) * 8] = f2bits(bits2f(rB0[j]) * rsf);
            Bn[buf][n1_ * YSTR2 + lrow + (n1_ >> 3) * 8] = f2bits(bits2f(rB1[j]) * rsf);
            Xt[buf][p_ * YSTR2 + lrow + (p_ >> 3) * 8] = rX[j];
        }
        if (ct < 64) { sdt2[buf][ct] = rdt; sAc2[buf][ct] = rsa; }
    };

    for (int i = tid; i < 32 * 68; i += 512) Sf[i] = 0.f;
    for (int i = tid; i < 32 * YSTR; i += 512) Sb[0][i] = 0;
    if (tid < NCH) etl[tid] = etg[(h * BSZ + b) * NCH + tid];
    if (prod) { load_chunk(0); scatter(0); }
    __syncthreads();

    for (int c = 0; c < NCH; c++) {
        const int par = c & 1, nb = par ^ 1;
        const int rows0 = b * SEQ + c * CKL;
        if (prod) {
            // stage chunk c+1 concurrently with consumers' chunk-c compute
            if (c + 1 < NCH) { load_chunk(c + 1); scatter(nb); }
        } else {
            float etot = etl[c];
            // own z row for chunk c (latency hidden under P1/P2)
            short8 zcur = *(const short8*)((const short*)zx + (size_t)(rows0 + zl) * N1 + xcol + zp);

            short8 cf0 = *(const short8*)&Ct[par][(16 * w + lr) * YSTR + lk * 8];
            short8 cf1 = *(const short8*)&Ct[par][(16 * w + lr) * YSTR + 32 + lk * 8];
            // P1: Y_off = C * S0^T
            f32x4 acc[2];
#pragma unroll
            for (int t = 0; t < 2; t++) {
                short8 s0 = *(const short8*)&Sb[par][(16 * t + lr) * YSTR + lk * 8];
                short8 s1 = *(const short8*)&Sb[par][(16 * t + lr) * YSTR + 32 + lk * 8];
                acc[t] = MF(cf0, s0, (f32x4){0.f, 0.f, 0.f, 0.f});
                acc[t] = MF(cf1, s1, acc[t]);
            }
            float sAcl[4], el[4];
#pragma unroll
            for (int rr = 0; rr < 4; rr++) { sAcl[rr] = sAc2[par][16 * w + lk * 4 + rr]; el[rr] = __expf(sAcl[rr]); }
#pragma unroll
            for (int t = 0; t < 2; t++)
#pragma unroll
                for (int rr = 0; rr < 4; rr++) acc[t][rr] *= el[rr];
            // P2: G = C * B^T, mask/decay, wave-private LDS round-trip
            short* gw = Gs + w * 16 * YSTR;
#pragma unroll
            for (int t = 0; t < 4; t++) {
                short8 b0 = *(const short8*)&Bt[par][(16 * t + lr) * YSTR + lk * 8];
                short8 b1 = *(const short8*)&Bt[par][(16 * t + lr) * YSTR + 32 + lk * 8];
                f32x4 g = MF(cf0, b0, (f32x4){0.f, 0.f, 0.f, 0.f});
                g = MF(cf1, b1, g);
                int s = 16 * t + lr;
                float sAcs = sAc2[par][s], dts = sdt2[par][s];
#pragma unroll
                for (int rr = 0; rr < 4; rr++) {
                    int l = 16 * w + lk * 4 + rr;
                    float v = (s <= l) ? g[rr] * __expf(sAcl[rr] - sAcs) * dts : 0.f;
                    gw[(lk * 4 + rr) * YSTR + s] = f2bits(v);
                }
            }
            // P3: Y += G * X
            short8 gf0 = *(const short8*)&gw[lr * YSTR + lk * 8];
            short8 gf1 = *(const short8*)&gw[lr * YSTR + 32 + lk * 8];
#pragma unroll
            for (int t = 0; t < 2; t++) {
                int xr = 16 * t + lr;
                short8 x0 = *(const short8*)&Xt[par][xr * YSTR2 + ((xr >> 3) + lk) * 8];
                short8 x1 = *(const short8*)&Xt[par][xr * YSTR2 + 32 + ((xr >> 3) + lk) * 8];
                acc[t] = MF(gf0, x0, acc[t]);
                acc[t] = MF(gf1, x1, acc[t]);
            }
            // P4: Snew = X * (B*sf)^T ; Sf = Sf*etot + Snew ; Sb[nb] = bf16(Sf)
            {
                int pw = w & 1, nh2 = w >> 1;
                const int xp = 16 * pw + lr;
                short8 xt0 = *(const short8*)&Xt[par][xp * YSTR2 + ((xp >> 3) + lk) * 8];
                short8 xt1 = *(const short8*)&Xt[par][xp * YSTR2 + 32 + ((xp >> 3) + lk) * 8];
#pragma unroll
                for (int j = 0; j < 2; j++) {
                    int nt = 2 * nh2 + j;
                    int nr = 16 * nt + lr;
                    short8 b0 = *(const short8*)&Bn[par][nr * YSTR2 + ((nr >> 3) + lk) * 8];
                    short8 b1 = *(const short8*)&Bn[par][nr * YSTR2 + 32 + ((nr >> 3) + lk) * 8];
                    f32x4 sacc = MF(xt0, b0, (f32x4){0.f, 0.f, 0.f, 0.f});
                    sacc = MF(xt1, b1, sacc);
#pragma unroll
                    for (int rr = 0; rr < 4; rr++) {
                        int n = 16 * nt + lr;
                        int p = 16 * pw + lk * 4 + rr;
                        float nv = Sf[p * 68 + n] * etot + sacc[rr];
                        Sf[p * 68 + n] = nv;
                        Sb[nb][p * YSTR + n] = f2bits(nv);
                    }
                }
            }
            // Y epilogue (+D*x) into Ct[par]'s own wave rows; coalesced z-gate
#pragma unroll
            for (int t = 0; t < 2; t++) {
#pragma unroll
                for (int rr = 0; rr < 4; rr++) {
                    int p = 16 * t + lr;
                    int l = 16 * w + lk * 4 + rr;
                    float y = acc[t][rr] + Dh * bits2f(Xt[par][p * YSTR2 + l + (p >> 3) * 8]);
                    Ct[par][l * YSTR + p] = f2bits(y);
                }
            }
            {
                short8 y8 = *(const short8*)&Ct[par][zl * YSTR + zp];
                short* zpp = (short*)zx + (size_t)(rows0 + zl) * N1 + xcol + zp;
                short8 o;
#pragma unroll
                for (int j = 0; j < 8; j++) {
                    float z = bits2f(zcur[j]);
                    o[j] = f2bits(bits2f(y8[j]) * (z * sigmoidf_(z)));
                }
                *(short8*)zpp = o;
            }
        }
        __syncthreads();
    }
}

extern "C" void kernel_launch(void* const* d_in, const int* in_sizes, int n_in,
                              void* d_out, int out_size, void* d_ws, size_t ws_size,
                              hipStream_t stream) {
    const float* u       = (const float*)d_in[0];
    const float* W_in    = (const float*)d_in[1];
    const float* conv_w  = (const float*)d_in[2];
    const float* conv_b  = (const float*)d_in[3];
    const float* dt_bias = (const float*)d_in[4];
    const float* A_log   = (const float*)d_in[5];
    const float* Dp      = (const float*)d_in[6];
    const float* norm_w  = (const float*)d_in[7];
    const float* W_out   = (const float*)d_in[8];
    float* out = (float*)d_out;

    // Workspace layout (~112 MiB total):
    char* ws = (char*)d_ws;
    bf16* zx     = (bf16*)ws;  ws += (size_t)MTOT * N1 * 2;       // 69.2 MB
    bf16* xbc    = (bf16*)ws;  ws += (size_t)MTOT * CONVD * 2;    // 35.7 MB
    bf16* wout_b = (bf16*)ws;  ws += (size_t)DMODEL * DINNER * 2; // 4 MB
    float* dtt   = (float*)ws; ws += (size_t)NH * MTOT * 4;       // 1 MB, [h][t]
    float* sAcw  = (float*)ws; ws += (size_t)NH * MTOT * 4;       // 1 MB
    float* sfvw  = (float*)ws; ws += (size_t)NH * MTOT * 4;       // 1 MB
    float* etotw = (float*)ws; ws += 64 * 1024;                   // 16 KB (padded)

    // d_out (32 MiB) doubles as scratch for GEMM1 inputs only.
    bf16* u_b   = (bf16*)d_out;                                      // 16 MB
    bf16* win_b = (bf16*)((char*)d_out + (size_t)MTOT * DMODEL * 2); // 8.25 MB

    // merged weight-convert + u-prep + dt projection (one launch)
    k_pre2<<<CVTB + MTOT / 8, 256, 0, stream>>>(u, W_in, dt_bias, W_out, norm_w,
                                                u_b, dtt, win_b, wout_b);
    // dt chunk-scan precompute
    k_dts<<<dim3(NH, BSZ), 256, 0, stream>>>(dtt, A_log, sAcw, sfvw, etotw);

    // GEMM1: 256x192 tiles, 8-phase counted-vmcnt pipeline (measured-best R7 version)
    k_g1<<<dim3(N1 / 192, MTOT / 256), 512, 0, stream>>>(u_b, win_b, zx);

    // depthwise conv, 4 rows/thread (full CONVD; measured-best R6 version)
    k_conv<<<(MTOT / 4) * (CONVD / 4) / 256, 256, 0, stream>>>(zx, conv_w, conv_b, xbc);

    // fused SSD scan: producer/consumer wave split (512 threads)
    k_ssd<<<dim3(2, NH, BSZ), 512, 0, stream>>>(xbc, dtt, sAcw, sfvw, etotw, Dp, zx);

    // GEMM2 (+RMS): 256x128 tiles, 3-buffer counted-vmcnt pipeline, zero tail
    k_g2<<<dim3(DMODEL / 128, MTOT / 256), 512, 0, stream>>>(zx, wout_b, out);
}